// Round 14
// baseline (283.039 us; speedup 1.0000x reference)
//
#include <hip/hip_runtime.h>
#include <cstdint>
#include <cstddef>

// ---------------- problem constants ----------------
constexpr int CB  = 8;     // batch
constexpr int CS  = 512;   // seq len
constexpr int CH  = 768;   // hidden
constexpr int CNH = 12;    // heads
constexpr int CDH = 64;    // head dim
constexpr int CFF = 3072;  // ffn dim
constexpr int CE  = 4;     // experts
constexpr int C3H = 3 * CH;  // 2304 fused QKV width

using f32x4  = __attribute__((ext_vector_type(4))) float;
using bf16x8 = __attribute__((ext_vector_type(8))) short;

__device__ __forceinline__ short f2bf(float x) {
  union { float f; uint32_t u; } v; v.f = x;
  return (short)((v.u + 0x7fffu + ((v.u >> 16) & 1u)) >> 16);  // RNE
}

__device__ __forceinline__ void gload_lds16(const void* g, void* l) {
  __builtin_amdgcn_global_load_lds((const __attribute__((address_space(1))) void*)g,
                                   (__attribute__((address_space(3))) void*)l,
                                   16, 0, 0);
}

#define VMCNT(n)  asm volatile("s_waitcnt vmcnt(" #n ")" ::: "memory")
#define SCHEDB()  __builtin_amdgcn_sched_barrier(0)

// ---------------- fp32 -> bf16 elementwise ----------------
__global__ void cvt_bf16_kernel(const float* __restrict__ in, short* __restrict__ out, int n4) {
  int i = blockIdx.x * blockDim.x + threadIdx.x;
  if (i < n4) {
    float4 v = ((const float4*)in)[i];
    short4 o;
    o.x = f2bf(v.x); o.y = f2bf(v.y); o.z = f2bf(v.z); o.w = f2bf(v.w);
    ((short4*)out)[i] = o;
  }
}

// ---------------- transpose+convert: W [K,N] f32 -> Wt [N,K] bf16 ------
__device__ __forceinline__ bool expert_used(const int* __restrict__ eidx, int e) {
  bool u = false;
#pragma unroll
  for (int s = 0; s < CB; ++s) u |= (eidx[s] == e);
  return u;
}

__device__ __forceinline__ void tpose_body(const float* __restrict__ Wb,
                                           short* __restrict__ Wtb, int K, int N) {
  __shared__ __align__(16) short Ts[64 * 68];
  const int n0 = blockIdx.x * 64, k0 = blockIdx.y * 64;
  const int t  = threadIdx.x;
  const int tn = t & 15, tk = t >> 4;
#pragma unroll
  for (int p = 0; p < 4; ++p) {
    int k = k0 + p * 16 + tk;
    float4 v = *(const float4*)(Wb + (size_t)k * N + n0 + tn * 4);
#pragma unroll
    for (int j = 0; j < 4; ++j)
      Ts[(tn * 4 + j) * 68 + p * 16 + tk] = f2bf(((const float*)&v)[j]);
  }
  __syncthreads();
#pragma unroll
  for (int p = 0; p < 4; ++p) {
    int n = n0 + p * 16 + tk;
    uint2 o = *(const uint2*)(Ts + (p * 16 + tk) * 68 + tn * 4);
    *(uint2*)(Wtb + (size_t)n * K + k0 + tn * 4) = o;
  }
}

__global__ void tpose_cvt_kernel(const float* __restrict__ W, short* __restrict__ Wt,
                                 const int* __restrict__ eidx, int K, int N) {
  const int e = blockIdx.z;
  if (!expert_used(eidx, e)) return;
  tpose_body(W + (size_t)e * K * N, Wt + (size_t)e * K * N, K, N);
}

__global__ void tpose4_kernel(const float* __restrict__ Wq, const float* __restrict__ Wk,
                              const float* __restrict__ Wv, const float* __restrict__ Wo,
                              const int* __restrict__ eidx,
                              short* __restrict__ Wqkvt, short* __restrict__ Wot) {
  const int z = blockIdx.z, e = z >> 2, m = z & 3;
  if (!expert_used(eidx, e)) return;
  const float* W = (m == 0) ? Wq : (m == 1) ? Wk : (m == 2) ? Wv : Wo;
  const float* Wb = W + (size_t)e * CH * CH;
  short* dst = (m == 3) ? (Wot + (size_t)e * CH * CH)
                        : (Wqkvt + ((size_t)e * C3H + m * CH) * CH);
  tpose_body(Wb, dst, CH, CH);
}

__global__ void qkv_bias_kernel(const float* __restrict__ bq, const float* __restrict__ bk,
                                const float* __restrict__ bv, float* __restrict__ dst) {
  int i = blockIdx.x * 256 + threadIdx.x;
  if (i >= CE * C3H) return;
  int e = i / C3H, r = i % C3H;
  int m = r / CH, c = r % CH;
  const float* s = (m == 0) ? bq : (m == 1) ? bk : bv;
  dst[i] = s[e * CH + c];
}

// ---------------- expert sort helper ----------------
__device__ __forceinline__ void expert_sort(const int* __restrict__ eidx,
                                            uint32_t& epack, uint32_t& sortedPack) {
  int exv[CB];
#pragma unroll
  for (int s = 0; s < CB; ++s) exv[s] = eidx[s];
  epack = 0;
#pragma unroll
  for (int s = 0; s < CB; ++s) epack |= (uint32_t)exv[s] << (2 * s);
  int c0 = 0, c1 = 0, c2 = 0;
#pragma unroll
  for (int s = 0; s < CB; ++s) {
    c0 += (exv[s] == 0); c1 += (exv[s] == 1); c2 += (exv[s] == 2);
  }
  int p0 = 0, p1 = c0, p2 = c0 + c1, p3 = c0 + c1 + c2;
  sortedPack = 0;
#pragma unroll
  for (int s = 0; s < CB; ++s) {
    int ee = exv[s];
    int p = (ee == 0) ? p0 : (ee == 1) ? p1 : (ee == 2) ? p2 : p3;
    sortedPack |= (uint32_t)s << (4 * p);
    p0 += (ee == 0); p1 += (ee == 1); p2 += (ee == 2); p3 += (ee == 3);
  }
}

// ---------------- L2-fit chunked, expert-sorted work decode (gemm8) --------
template <int BM, int NTN, int KSPLIT, int NJB, int NNB>
__device__ __forceinline__ void moe_decode(const int* __restrict__ eidx,
                                           int& e, int& mrow0, int& nt, int& ks) {
  constexpr int JC  = 4096 / BM;
  constexpr int MTS = CS / BM;
  constexpr int CHJ = JC / NJB;
  constexpr int CHN = NTN / NNB;
  constexpr int NKB = 8 / (NJB * NNB);
  constexpr int CHK = KSPLIT / NKB;
  uint32_t epack, sortedPack;
  expert_sort(eidx, epack, sortedPack);
  const int x = (int)blockIdx.x & 7;
  const int i = (int)blockIdx.x >> 3;
  const int kb = x / (NJB * NNB);
  const int rx = x - kb * (NJB * NNB);
  const int jb = rx / NNB, nb = rx - (rx / NNB) * NNB;
  const int nn = i % CHN;
  const int rem = i / CHN;
  const int jj = rem % CHJ;
  const int kk2 = rem / CHJ;
  const int j = jb * CHJ + jj;
  nt = nb * CHN + nn;
  ks = kb * CHK + kk2;
  const int sample = (int)((sortedPack >> (4 * (j / MTS))) & 7);
  e = (int)((epack >> (2 * sample)) & 3);
  mrow0 = sample * CS + (j % MTS) * BM;
}

// ---------------- gemmd: DIRECT no-LDS GEMM, wave-owned 64x64 tiles --------
// Rationale (R13 counters): per-XCD working set is L2-resident (FETCH 18 MB
// vs 300 MB staged) -> LDS staging is pure overhead (Common-mistake #7).
// Per wave: 64x64 output, per K-step (32 elems) 8x global_load_dwordx4
// (A/B frags straight from L2: 16 rows x 64 B per frag-quad, coalesced
// 64 B segments) + 16 MFMA.  No LDS, no barriers, no waitcnt discipline —
// TLP (4 waves/SIMD) hides the ~200 cy L2 latency.  Block = 1 j-tile x 4
// adjacent col-tiles (waves share the A-panel via L2/L1).  Expert-sorted,
// XCD L2-fit chunked as before.
template <int K, int NTG, int NJB, int NNB, int ACT, bool OB16>
__global__ __launch_bounds__(256, 4)
void gemmd_kernel(const short* __restrict__ A, const short* __restrict__ Wt,
                  const float* __restrict__ bias, const int* __restrict__ eidx,
                  char* __restrict__ out,
                  size_t wtExpStride, int biasStride, int outLd) {
  constexpr int JC = 64, MTS = 8;          // 4096/64, 512/64
  constexpr int CHJ = JC / NJB, CHG = NTG / NNB;
  const int t = threadIdx.x, w = t >> 6, l = t & 63, lr = l & 15, lg = l >> 4;

  uint32_t epack, sortedPack;
  expert_sort(eidx, epack, sortedPack);
  const int x = (int)blockIdx.x & 7;
  const int i = (int)blockIdx.x >> 3;
  const int jb = x / NNB, nb = x % NNB;    // NJB*NNB == 8
  const int gg = i % CHG, jj = i / CHG;
  const int j = jb * CHJ + jj;
  const int ntile = (nb * CHG + gg) * 4 + w;       // this wave's 64-col tile
  const int sample = (int)((sortedPack >> (4 * (j / MTS))) & 7);
  const int e = (int)((epack >> (2 * sample)) & 3);
  const int mrow0 = sample * CS + (j % MTS) * 64;

  const short* Ab = A + (size_t)mrow0 * K;
  const short* Bb = Wt + (size_t)e * wtExpStride + (size_t)(ntile * 64) * K;
  const int laneoff = lr * K + lg * 8;             // elements

  f32x4 acc[4][4] = {};

  for (int kt = 0; kt < K / 32; ++kt) {
    const int ko = kt * 32 + laneoff;
    bf16x8 af[4], bfr[4];
#pragma unroll
    for (int mi = 0; mi < 4; ++mi)
      af[mi] = *(const bf16x8*)(Ab + (size_t)mi * 16 * K + ko);
#pragma unroll
    for (int ni = 0; ni < 4; ++ni)
      bfr[ni] = *(const bf16x8*)(Bb + (size_t)ni * 16 * K + ko);
#pragma unroll
    for (int mi = 0; mi < 4; ++mi)
#pragma unroll
      for (int ni = 0; ni < 4; ++ni)
        acc[mi][ni] = __builtin_amdgcn_mfma_f32_16x16x32_bf16(af[mi], bfr[ni],
                                                              acc[mi][ni], 0, 0, 0);
  }

  // epilogue
#pragma unroll
  for (int ni = 0; ni < 4; ++ni) {
    const int col = ntile * 64 + ni * 16 + lr;
    const float bv = bias ? bias[e * biasStride + col] : 0.0f;
#pragma unroll
    for (int mi = 0; mi < 4; ++mi) {
      const int row0 = mrow0 + mi * 16 + lg * 4;
#pragma unroll
      for (int r = 0; r < 4; ++r) {
        float v = acc[mi][ni][r] + bv;
        if (ACT == 1) v = 0.5f * v * (1.0f + erff(v * 0.70710678118654752f));  // exact GELU
        if (OB16) ((short*)out)[(size_t)(row0 + r) * outLd + col] = f2bf(v);
        else      ((float*)out)[(size_t)(row0 + r) * outLd + col] = v;
      }
    }
  }
}

// ---------------- gemm8: 128x192 tile, BK=128, SINGLE buffer, 256 thr ------
// (retained for O-proj and FFN2 — R11/R13-verified)
template <int K, int NTN, int KSPLIT, int NJB, int NNB, int ACT, bool OB16>
__global__ __launch_bounds__(256, 2)
void gemm8_kernel(const short* __restrict__ A, const short* __restrict__ Wt,
                  const float* __restrict__ bias, const int* __restrict__ eidx,
                  char* __restrict__ out, char* __restrict__ out2,
                  size_t wtExpStride, int biasStride, int outLd, size_t outKsStride) {
  constexpr int BM = 128, BN = 192;
  constexpr int MI = 4, NI = 6;
  constexpr int NT = K / KSPLIT / 128;
  __shared__ __align__(16) short As[BM * 128];     // 32 KB
  __shared__ __align__(16) short Bs[BN * 128];     // 48 KB
  const int t = threadIdx.x, w = t >> 6, l = t & 63, lr = l & 15, lg = l >> 4;

  int e, mrow0, nt, ks;
  moe_decode<BM, NTN, KSPLIT, NJB, NNB>(eidx, e, mrow0, nt, ks);
  const int kBase = ks * NT * 128;

  const int srow = t >> 4;
  const int gcol = ((t & 15) ^ srow) * 8;
  const short* aSrc = A + (size_t)(mrow0 + srow) * K + kBase + gcol;
  const short* bSrc = Wt + (size_t)e * wtExpStride + (size_t)(nt * BN + srow) * K + kBase + gcol;
  const size_t iss16 = (size_t)16 * K;

  const int wrow = (w >> 1) * 64, wn = (w & 1) * 96;
  int aoff[4][MI], boff[4][NI];
#pragma unroll
  for (int kk = 0; kk < 4; ++kk) {
    const int c = (kk * 4 + lg) ^ lr;
#pragma unroll
    for (int mi = 0; mi < MI; ++mi)
      aoff[kk][mi] = (wrow + mi * 16 + lr) * 128 + c * 8;
#pragma unroll
    for (int ni = 0; ni < NI; ++ni)
      boff[kk][ni] = (wn + ni * 16 + lr) * 128 + c * 8;
  }

  f32x4 acc[MI][NI] = {};

  for (int kt = 0; kt < NT; ++kt) {
    {
      const short* as = aSrc + (size_t)kt * 128;
#pragma unroll
      for (int i = 0; i < 8; ++i)
        gload_lds16(as + i * iss16, &As[i * 2048 + t * 8]);
      const short* bs = bSrc + (size_t)kt * 128;
#pragma unroll
      for (int i = 0; i < 12; ++i)
        gload_lds16(bs + i * iss16, &Bs[i * 2048 + t * 8]);
    }
    VMCNT(0);
    __builtin_amdgcn_s_barrier();
    SCHEDB();
#pragma unroll
    for (int kk = 0; kk < 4; ++kk) {
      bf16x8 af[MI], bfr[NI];
#pragma unroll
      for (int ni = 0; ni < NI; ++ni) bfr[ni] = *(const bf16x8*)(&Bs[boff[kk][ni]]);
#pragma unroll
      for (int mi = 0; mi < MI; ++mi) af[mi] = *(const bf16x8*)(&As[aoff[kk][mi]]);
      __builtin_amdgcn_s_setprio(1);
#pragma unroll
      for (int mi = 0; mi < MI; ++mi)
#pragma unroll
        for (int ni = 0; ni < NI; ++ni)
          acc[mi][ni] = __builtin_amdgcn_mfma_f32_16x16x32_bf16(af[mi], bfr[ni],
                                                                acc[mi][ni], 0, 0, 0);
      __builtin_amdgcn_s_setprio(0);
    }
    __builtin_amdgcn_s_barrier();
    SCHEDB();
  }

  float* outF = (ks < 2) ? ((float*)out + (size_t)ks * outKsStride)
                         : ((float*)out2 + (size_t)(ks - 2) * outKsStride);
#pragma unroll
  for (int ni = 0; ni < NI; ++ni) {
    const int col = nt * BN + wn + ni * 16 + lr;
    const float bv = bias ? bias[e * biasStride + col] : 0.0f;
#pragma unroll
    for (int mi = 0; mi < MI; ++mi) {
      const int row0 = mrow0 + wrow + mi * 16 + lg * 4;
#pragma unroll
      for (int r = 0; r < 4; ++r) {
        float v = acc[mi][ni][r] + bv;
        if (ACT == 1) v = 0.5f * v * (1.0f + erff(v * 0.70710678118654752f));
        if (OB16) ((short*)out)[(size_t)(row0 + r) * outLd + col] = f2bf(v);
        else      outF[(size_t)(row0 + r) * outLd + col] = v;
      }
    }
  }
}

// ---------------- fused attention ----------------
__global__ void attn_kernel(const short* __restrict__ QKV, const float* __restrict__ mask,
                            short* __restrict__ ctx) {
  __shared__ __align__(16) short Vt[2][64 * 40];
  __shared__ __align__(16) short Pt[4][2][16 * 40];
  const int bh = blockIdx.x;
  const int b = bh / CNH, h = bh % CNH;
  const int qt = blockIdx.y;
  const int t = threadIdx.x, w = t >> 6, l = t & 63, lr = l & 15, lg = l >> 4;

  const size_t bS = (size_t)b * CS;
  const short* Qh = QKV + bS * C3H + h * CDH;
  const short* Kh = Qh + CH;
  const short* Vh = Qh + 2 * CH;
  const float* mrow = mask + bS;

  const int qrow = qt * 64 + w * 16 + lr;
  bf16x8 qa[2];
  qa[0] = *(const bf16x8*)(Qh + (size_t)qrow * C3H + lg * 8);
  qa[1] = *(const bf16x8*)(Qh + (size_t)qrow * C3H + 32 + lg * 8);

  f32x4 o[4] = {};
  float lp[4] = {0.f, 0.f, 0.f, 0.f};

  const int dh = t & 63, kg = t >> 6;
  {
    short v8[8];
#pragma unroll
    for (int j = 0; j < 8; ++j) v8[j] = Vh[(size_t)(kg * 8 + j) * C3H + dh];
    uint32_t p0 = (uint32_t)(uint16_t)v8[0] | ((uint32_t)(uint16_t)v8[1] << 16);
    uint32_t p1 = (uint32_t)(uint16_t)v8[2] | ((uint32_t)(uint16_t)v8[3] << 16);
    uint32_t p2 = (uint32_t)(uint16_t)v8[4] | ((uint32_t)(uint16_t)v8[5] << 16);
    uint32_t p3 = (uint32_t)(uint16_t)v8[6] | ((uint32_t)(uint16_t)v8[7] << 16);
    uint4 pk = {p0, p1, p2, p3};
    *(uint4*)(&Vt[0][dh * 40 + kg * 8]) = pk;
  }

  for (int tt = 0; tt < CS / 32; ++tt) {
    const int k0 = tt * 32;
    __syncthreads();

    f32x4 sacc[2] = {};
#pragma unroll
    for (int n = 0; n < 2; ++n) {
      bf16x8 kb0 = *(const bf16x8*)(Kh + (size_t)(k0 + n * 16 + lr) * C3H + lg * 8);
      bf16x8 kb1 = *(const bf16x8*)(Kh + (size_t)(k0 + n * 16 + lr) * C3H + 32 + lg * 8);
      sacc[n] = __builtin_amdgcn_mfma_f32_16x16x32_bf16(qa[0], kb0, sacc[n], 0, 0, 0);
      sacc[n] = __builtin_amdgcn_mfma_f32_16x16x32_bf16(qa[1], kb1, sacc[n], 0, 0, 0);
    }

    if (tt + 1 < CS / 32) {
      const int k1 = k0 + 32;
      short v8[8];
#pragma unroll
      for (int j = 0; j < 8; ++j) v8[j] = Vh[(size_t)(k1 + kg * 8 + j) * C3H + dh];
      uint32_t p0 = (uint32_t)(uint16_t)v8[0] | ((uint32_t)(uint16_t)v8[1] << 16);
      uint32_t p1 = (uint32_t)(uint16_t)v8[2] | ((uint32_t)(uint16_t)v8[3] << 16);
      uint32_t p2 = (uint32_t)(uint16_t)v8[4] | ((uint32_t)(uint16_t)v8[5] << 16);
      uint32_t p3 = (uint32_t)(uint16_t)v8[6] | ((uint32_t)(uint16_t)v8[7] << 16);
      uint4 pk = {p0, p1, p2, p3};
      *(uint4*)(&Vt[(tt + 1) & 1][dh * 40 + kg * 8]) = pk;
    }

    const int pb = tt & 1;
#pragma unroll
    for (int n = 0; n < 2; ++n) {
      float mv = mrow[k0 + n * 16 + lr];
#pragma unroll
      for (int r = 0; r < 4; ++r) {
        float s = sacc[n][r] * 0.125f + mv;
        float e = __expf(s);
        lp[r] += e;
        Pt[w][pb][(lg * 4 + r) * 40 + n * 16 + lr] = f2bf(e);
      }
    }

    bf16x8 pa = *(const bf16x8*)(&Pt[w][pb][lr * 40 + lg * 8]);
#pragma unroll
    for (int d = 0; d < 4; ++d) {
      bf16x8 vbf = *(const bf16x8*)(&Vt[tt & 1][(d * 16 + lr) * 40 + lg * 8]);
      o[d] = __builtin_amdgcn_mfma_f32_16x16x32_bf16(pa, vbf, o[d], 0, 0, 0);
    }
  }

#pragma unroll
  for (int r = 0; r < 4; ++r) {
    float s = lp[r];
    s += __shfl_xor(s, 1); s += __shfl_xor(s, 2);
    s += __shfl_xor(s, 4); s += __shfl_xor(s, 8);
    lp[r] = 1.0f / s;
  }
#pragma unroll
  for (int d = 0; d < 4; ++d)
#pragma unroll
    for (int r = 0; r < 4; ++r) {
      int row = qt * 64 + w * 16 + lg * 4 + r;
      ctx[(bS + row) * CH + h * CDH + d * 16 + lr] = f2bf(o[d][r] * lp[r]);
    }
}

// ---------------- unified LN: NP split-K partials + expert bias + residual
// -> LayerNorm -> f32 out (+ optional bf16 out) -------------------
template <int NP>
__global__ void ln12_kernel(const float* __restrict__ p0, const float* __restrict__ p1,
                            const float* __restrict__ p2, const float* __restrict__ p3,
                            const float* __restrict__ res,
                            const float* __restrict__ btab, const int* __restrict__ eidx,
                            const float* __restrict__ g, const float* __restrict__ bta,
                            float* __restrict__ out32, short* __restrict__ out16) {
  const int row = blockIdx.x;
  const int l = threadIdx.x;
  const int e = eidx[row >> 9];
  const float* xr0 = p0 + (size_t)row * CH;
  const float* xr1 = p1 + (size_t)row * CH;
  const float* rr  = res + (size_t)row * CH;
  const float* bo  = btab + (size_t)e * CH;
  float4 v[3];
  float sum = 0.f, ss = 0.f;
#pragma unroll
  for (int j = 0; j < 3; ++j) {
    float4 a = *(const float4*)(xr0 + j * 256 + l * 4);
    float4 c = *(const float4*)(xr1 + j * 256 + l * 4);
    float4 b = *(const float4*)(rr + j * 256 + l * 4);
    float4 bb = *(const float4*)(bo + j * 256 + l * 4);
    a.x += c.x + b.x + bb.x; a.y += c.y + b.y + bb.y;
    a.z += c.z + b.z + bb.z; a.w += c.w + b.w + bb.w;
    if (NP >= 3) {
      float4 d2 = *(const float4*)(p2 + (size_t)row * CH + j * 256 + l * 4);
      a.x += d2.x; a.y += d2.y; a.z += d2.z; a.w += d2.w;
    }
    if (NP == 4) {
      float4 d3 = *(const float4*)(p3 + (size_t)row * CH + j * 256 + l * 4);
      a.x += d3.x; a.y += d3.y; a.z += d3.z; a.w += d3.w;
    }
    v[j] = a;
    sum += a.x + a.y + a.z + a.w;
    ss  += a.x * a.x + a.y * a.y + a.z * a.z + a.w * a.w;
  }
#pragma unroll
  for (int m = 1; m < 64; m <<= 1) { sum += __shfl_xor(sum, m); ss += __shfl_xor(ss, m); }
  const float mean = sum * (1.0f / CH);
  const float var  = ss * (1.0f / CH) - mean * mean;
  const float rstd = rsqrtf(var + 1e-12f);
#pragma unroll
  for (int j = 0; j < 3; ++j) {
    float4 gg = *(const float4*)(g   + j * 256 + l * 4);
    float4 bb = *(const float4*)(bta + j * 256 + l * 4);
    float4 a = v[j], y;
    y.x = (a.x - mean) * rstd * gg.x + bb.x;
    y.y = (a.y - mean) * rstd * gg.y + bb.y;
    y.z = (a.z - mean) * rstd * gg.z + bb.z;
    y.w = (a.w - mean) * rstd * gg.w + bb.w;
    *(float4*)(out32 + (size_t)row * CH + j * 256 + l * 4) = y;
    if (out16) {
      short4 o;
      o.x = f2bf(y.x); o.y = f2bf(y.y); o.z = f2bf(y.z); o.w = f2bf(y.w);
      *(short4*)(out16 + (size_t)row * CH + j * 256 + l * 4) = o;
    }
  }
}

// ---------------- launcher ----------------
extern "C" void kernel_launch(void* const* d_in, const int* in_sizes, int n_in,
                              void* d_out, int out_size, void* d_ws, size_t ws_size,
                              hipStream_t stream) {
  (void)in_sizes; (void)n_in; (void)out_size; (void)ws_size;
  const float* hidden = (const float*)d_in[0];
  const int*   eidx   = (const int*)d_in[1];
  const float* mask   = (const float*)d_in[2];
  const float* Wq   = (const float*)d_in[3];
  const float* bq   = (const float*)d_in[4];
  const float* Wk   = (const float*)d_in[5];
  const float* bk   = (const float*)d_in[6];
  const float* Wv   = (const float*)d_in[7];
  const float* bv   = (const float*)d_in[8];
  const float* Wo   = (const float*)d_in[9];
  const float* bo   = (const float*)d_in[10];
  const float* ln1g = (const float*)d_in[11];
  const float* ln1b = (const float*)d_in[12];
  const float* Wi   = (const float*)d_in[13];
  const float* bi   = (const float*)d_in[14];
  const float* Wout = (const float*)d_in[15];
  const float* bout = (const float*)d_in[16];
  const float* ln2g = (const float*)d_in[17];
  const float* ln2b = (const float*)d_in[18];

  char* ws = (char*)d_ws;
  size_t off = 0;
  auto alloc = [&](size_t bytes) {
    void* p = ws + off;
    off += (bytes + 255) & ~(size_t)255;
    return p;
  };
  const size_t M = (size_t)CB * CS;                    // 4096 rows
  short* Xb    = (short*)alloc(M * CH * 2);            // later reused as x1b
  char*  Rbig  = (char*)alloc(M * CFF * 2);            // QKVb then hmid
  char*  Rcx   = (char*)alloc(M * CH * 4);             // ctxb then x1
  float* parts = (float*)alloc(2 * M * CH * 4);        // split-K partials 0,1
  float* qkvbias = (float*)alloc(CE * C3H * 4);
  short* Wqkvt = (short*)alloc((size_t)CE * C3H * CH * 2);  // 14.2 MB
  short* Wot   = (short*)alloc((size_t)CE * CH * CH * 2);   // 4.7 MB
  short* Wit   = (short*)alloc((size_t)CE * CH * CFF * 2);  // 18.9 MB
  short* Wo2t  = (short*)alloc((size_t)CE * CFF * CH * 2);
  short* QKVb = (short*)Rbig;
  short* hmid = (short*)Rbig;
  short* ctxb = (short*)Rcx;
  float* x1   = (float*)Rcx;
  short* x1b  = Xb;
  // Extra partials overlay dead weight regions (Wqkvt dead after QKV).
  float* pp2  = (float*)Wqkvt;
  float* pp3  = pp2 + M * CH;

  // 1. prep
  const int n4 = (int)(M * CH / 4);
  cvt_bf16_kernel<<<(n4 + 255) / 256, 256, 0, stream>>>(hidden, Xb, n4);
  tpose4_kernel<<<dim3(CH / 64, CH / 64, 4 * CE), 256, 0, stream>>>(Wq, Wk, Wv, Wo, eidx, Wqkvt, Wot);
  tpose_cvt_kernel<<<dim3(CFF / 64, CH / 64, CE), 256, 0, stream>>>(Wi, Wit, eidx, CH, CFF);
  tpose_cvt_kernel<<<dim3(CH / 64, CFF / 64, CE), 256, 0, stream>>>(Wout, Wo2t, eidx, CFF, CH);
  qkv_bias_kernel<<<(CE * C3H + 255) / 256, 256, 0, stream>>>(bq, bk, bv, qkvbias);

  // 2. QKV fused GEMM: gemmd direct, NTG=9 (2304/256), NJB=8 NNB=1 -> grid 576
  gemmd_kernel<CH, 9, 8, 1, 0, true><<<576, 256, 0, stream>>>(
      Xb, Wqkvt, qkvbias, eidx, (char*)QKVb, (size_t)C3H * CH, C3H, C3H);
  // 3. attention
  attn_kernel<<<dim3(CB * CNH, CS / 64), 256, 0, stream>>>(QKVb, mask, ctxb);
  // 4. O projection: gemm8 splitK3 -> grid 384 (R13 config)
  gemm8_kernel<CH, 4, 3, 4, 2, 0, false><<<384, 256, 0, stream>>>(
      ctxb, Wot, nullptr, eidx, (char*)parts, (char*)pp2, (size_t)CH * CH, CH, CH, M * CH);
  // 5. LN1 (3 partials + bo + residual hidden) -> x1 f32 + x1b bf16
  ln12_kernel<3><<<(int)M, 64, 0, stream>>>(parts, parts + M * CH, pp2, nullptr,
                                            hidden, bo, eidx, ln1g, ln1b, x1, x1b);
  // 6. FFN intermediate + GELU: gemmd direct, NTG=12 (3072/256), NJB=4 NNB=2 -> grid 768
  gemmd_kernel<CH, 12, 4, 2, 1, true><<<768, 256, 0, stream>>>(
      x1b, Wit, bi, eidx, (char*)hmid, (size_t)CH * CFF, CFF, CFF);
  // 7. FFN output: gemm8 splitK4 (NT=3), grid 512; partials 2,3 -> pp2, pp3
  gemm8_kernel<CFF, 4, 4, 2, 1, 0, false><<<512, 256, 0, stream>>>(
      hmid, Wo2t, nullptr, eidx, (char*)parts, (char*)pp2, (size_t)CFF * CH, CH, CH, M * CH);
  // 8. LN2 (4 partials + bout + residual x1) -> d_out
  ln12_kernel<4><<<(int)M, 64, 0, stream>>>(parts, parts + M * CH, pp2, pp3,
                                            x1, bout, eidx, ln2g, ln2b, (float*)d_out, nullptr);
}

// Round 15
// 183.430 us; speedup vs baseline: 1.5430x; 1.5430x over previous
//
#include <hip/hip_runtime.h>
#include <cstdint>
#include <cstddef>

// ---------------- problem constants ----------------
constexpr int CB  = 8;     // batch
constexpr int CS  = 512;   // seq len
constexpr int CH  = 768;   // hidden
constexpr int CNH = 12;    // heads
constexpr int CDH = 64;    // head dim
constexpr int CFF = 3072;  // ffn dim
constexpr int CE  = 4;     // experts
constexpr int C3H = 3 * CH;  // 2304 fused QKV width

using f32x4  = __attribute__((ext_vector_type(4))) float;
using bf16x8 = __attribute__((ext_vector_type(8))) short;

__device__ __forceinline__ short f2bf(float x) {
  union { float f; uint32_t u; } v; v.f = x;
  return (short)((v.u + 0x7fffu + ((v.u >> 16) & 1u)) >> 16);  // RNE
}

__device__ __forceinline__ void gload_lds16(const void* g, void* l) {
  __builtin_amdgcn_global_load_lds((const __attribute__((address_space(1))) void*)g,
                                   (__attribute__((address_space(3))) void*)l,
                                   16, 0, 0);
}

#define VMCNT(n)  asm volatile("s_waitcnt vmcnt(" #n ")" ::: "memory")
#define SCHEDB()  __builtin_amdgcn_sched_barrier(0)

// ---------------- fp32 -> bf16 elementwise ----------------
__global__ void cvt_bf16_kernel(const float* __restrict__ in, short* __restrict__ out, int n4) {
  int i = blockIdx.x * blockDim.x + threadIdx.x;
  if (i < n4) {
    float4 v = ((const float4*)in)[i];
    short4 o;
    o.x = f2bf(v.x); o.y = f2bf(v.y); o.z = f2bf(v.z); o.w = f2bf(v.w);
    ((short4*)out)[i] = o;
  }
}

// ---------------- transpose+convert: W [K,N] f32 -> Wt [N,K] bf16 ------
__device__ __forceinline__ bool expert_used(const int* __restrict__ eidx, int e) {
  bool u = false;
#pragma unroll
  for (int s = 0; s < CB; ++s) u |= (eidx[s] == e);
  return u;
}

__device__ __forceinline__ void tpose_body(const float* __restrict__ Wb,
                                           short* __restrict__ Wtb, int K, int N) {
  __shared__ __align__(16) short Ts[64 * 68];
  const int n0 = blockIdx.x * 64, k0 = blockIdx.y * 64;
  const int t  = threadIdx.x;
  const int tn = t & 15, tk = t >> 4;
#pragma unroll
  for (int p = 0; p < 4; ++p) {
    int k = k0 + p * 16 + tk;
    float4 v = *(const float4*)(Wb + (size_t)k * N + n0 + tn * 4);
#pragma unroll
    for (int j = 0; j < 4; ++j)
      Ts[(tn * 4 + j) * 68 + p * 16 + tk] = f2bf(((const float*)&v)[j]);
  }
  __syncthreads();
#pragma unroll
  for (int p = 0; p < 4; ++p) {
    int n = n0 + p * 16 + tk;
    uint2 o = *(const uint2*)(Ts + (p * 16 + tk) * 68 + tn * 4);
    *(uint2*)(Wtb + (size_t)n * K + k0 + tn * 4) = o;
  }
}

__global__ void tpose_cvt_kernel(const float* __restrict__ W, short* __restrict__ Wt,
                                 const int* __restrict__ eidx, int K, int N) {
  const int e = blockIdx.z;
  if (!expert_used(eidx, e)) return;
  tpose_body(W + (size_t)e * K * N, Wt + (size_t)e * K * N, K, N);
}

__global__ void tpose4_kernel(const float* __restrict__ Wq, const float* __restrict__ Wk,
                              const float* __restrict__ Wv, const float* __restrict__ Wo,
                              const int* __restrict__ eidx,
                              short* __restrict__ Wqkvt, short* __restrict__ Wot) {
  const int z = blockIdx.z, e = z >> 2, m = z & 3;
  if (!expert_used(eidx, e)) return;
  const float* W = (m == 0) ? Wq : (m == 1) ? Wk : (m == 2) ? Wv : Wo;
  const float* Wb = W + (size_t)e * CH * CH;
  short* dst = (m == 3) ? (Wot + (size_t)e * CH * CH)
                        : (Wqkvt + ((size_t)e * C3H + m * CH) * CH);
  tpose_body(Wb, dst, CH, CH);
}

__global__ void qkv_bias_kernel(const float* __restrict__ bq, const float* __restrict__ bk,
                                const float* __restrict__ bv, float* __restrict__ dst) {
  int i = blockIdx.x * 256 + threadIdx.x;
  if (i >= CE * C3H) return;
  int e = i / C3H, r = i % C3H;
  int m = r / CH, c = r % CH;
  const float* s = (m == 0) ? bq : (m == 1) ? bk : bv;
  dst[i] = s[e * CH + c];
}

// ---------------- expert sort helper ----------------
__device__ __forceinline__ void expert_sort(const int* __restrict__ eidx,
                                            uint32_t& epack, uint32_t& sortedPack) {
  int exv[CB];
#pragma unroll
  for (int s = 0; s < CB; ++s) exv[s] = eidx[s];
  epack = 0;
#pragma unroll
  for (int s = 0; s < CB; ++s) epack |= (uint32_t)exv[s] << (2 * s);
  int c0 = 0, c1 = 0, c2 = 0;
#pragma unroll
  for (int s = 0; s < CB; ++s) {
    c0 += (exv[s] == 0); c1 += (exv[s] == 1); c2 += (exv[s] == 2);
  }
  int p0 = 0, p1 = c0, p2 = c0 + c1, p3 = c0 + c1 + c2;
  sortedPack = 0;
#pragma unroll
  for (int s = 0; s < CB; ++s) {
    int ee = exv[s];
    int p = (ee == 0) ? p0 : (ee == 1) ? p1 : (ee == 2) ? p2 : p3;
    sortedPack |= (uint32_t)s << (4 * p);
    p0 += (ee == 0); p1 += (ee == 1); p2 += (ee == 2); p3 += (ee == 3);
  }
}

// ---------------- L2-fit chunked, expert-sorted work decode ----------
template <int BM, int NTN, int KSPLIT, int NJB, int NNB>
__device__ __forceinline__ void moe_decode(const int* __restrict__ eidx,
                                           int& e, int& mrow0, int& nt, int& ks) {
  constexpr int JC  = 4096 / BM;
  constexpr int MTS = CS / BM;
  constexpr int CHJ = JC / NJB;
  constexpr int CHN = NTN / NNB;
  constexpr int NKB = 8 / (NJB * NNB);
  constexpr int CHK = KSPLIT / NKB;
  uint32_t epack, sortedPack;
  expert_sort(eidx, epack, sortedPack);
  const int x = (int)blockIdx.x & 7;
  const int i = (int)blockIdx.x >> 3;
  const int kb = x / (NJB * NNB);
  const int rx = x - kb * (NJB * NNB);
  const int jb = rx / NNB, nb = rx - (rx / NNB) * NNB;
  const int nn = i % CHN;
  const int rem = i / CHN;
  const int jj = rem % CHJ;
  const int kk2 = rem / CHJ;
  const int j = jb * CHJ + jj;
  nt = nb * CHN + nn;
  ks = kb * CHK + kk2;
  const int sample = (int)((sortedPack >> (4 * (j / MTS))) & 7);
  e = (int)((epack >> (2 * sample)) & 3);
  mrow0 = sample * CS + (j % MTS) * BM;
}

// ---------------- gemm8: 128x192 tile, BK=128, SINGLE buffer, 256 thr ------
// FINAL (R11-verified best).  80 KB LDS -> 2 blocks/CU; per K-tile:
// STAGE(20 gload_lds/thread) -> vmcnt(0)+barrier -> 4 k-chunks x 24 MFMA ->
// barrier.  Single-buffer serialization covered by co-resident block (m114).
// Both-sides XOR swizzle chunk^(row&15): 0 bank conflicts.  Expert-sorted,
// XCD L2-fit chunked.  The ~4.7 B/cy/resident-block staging rate is the CU
// vector-memory request path limit (R14's no-LDS variant at 2x time proved
// staging amortization is required; 7 schedule variants could not beat it).
template <int K, int NTN, int KSPLIT, int NJB, int NNB, int ACT, bool OB16>
__global__ __launch_bounds__(256, 2)
void gemm8_kernel(const short* __restrict__ A, const short* __restrict__ Wt,
                  const float* __restrict__ bias, const int* __restrict__ eidx,
                  char* __restrict__ out, char* __restrict__ out2,
                  size_t wtExpStride, int biasStride, int outLd, size_t outKsStride) {
  constexpr int BM = 128, BN = 192;
  constexpr int MI = 4, NI = 6;
  constexpr int NT = K / KSPLIT / 128;
  __shared__ __align__(16) short As[BM * 128];     // 32 KB
  __shared__ __align__(16) short Bs[BN * 128];     // 48 KB
  const int t = threadIdx.x, w = t >> 6, l = t & 63, lr = l & 15, lg = l >> 4;

  int e, mrow0, nt, ks;
  moe_decode<BM, NTN, KSPLIT, NJB, NNB>(eidx, e, mrow0, nt, ks);
  const int kBase = ks * NT * 128;

  const int srow = t >> 4;                              // 0..15
  const int gcol = ((t & 15) ^ srow) * 8;               // swizzled k-elem offset
  const short* aSrc = A + (size_t)(mrow0 + srow) * K + kBase + gcol;
  const short* bSrc = Wt + (size_t)e * wtExpStride + (size_t)(nt * BN + srow) * K + kBase + gcol;
  const size_t iss16 = (size_t)16 * K;

  const int wrow = (w >> 1) * 64, wn = (w & 1) * 96;
  int aoff[4][MI], boff[4][NI];
#pragma unroll
  for (int kk = 0; kk < 4; ++kk) {
    const int c = (kk * 4 + lg) ^ lr;
#pragma unroll
    for (int mi = 0; mi < MI; ++mi)
      aoff[kk][mi] = (wrow + mi * 16 + lr) * 128 + c * 8;
#pragma unroll
    for (int ni = 0; ni < NI; ++ni)
      boff[kk][ni] = (wn + ni * 16 + lr) * 128 + c * 8;
  }

  f32x4 acc[MI][NI] = {};

  for (int kt = 0; kt < NT; ++kt) {
    {
      const short* as = aSrc + (size_t)kt * 128;
#pragma unroll
      for (int i = 0; i < 8; ++i)
        gload_lds16(as + i * iss16, &As[i * 2048 + t * 8]);
      const short* bs = bSrc + (size_t)kt * 128;
#pragma unroll
      for (int i = 0; i < 12; ++i)
        gload_lds16(bs + i * iss16, &Bs[i * 2048 + t * 8]);
    }
    VMCNT(0);
    __builtin_amdgcn_s_barrier();
    SCHEDB();
#pragma unroll
    for (int kk = 0; kk < 4; ++kk) {
      bf16x8 af[MI], bfr[NI];
#pragma unroll
      for (int ni = 0; ni < NI; ++ni) bfr[ni] = *(const bf16x8*)(&Bs[boff[kk][ni]]);
#pragma unroll
      for (int mi = 0; mi < MI; ++mi) af[mi] = *(const bf16x8*)(&As[aoff[kk][mi]]);
      __builtin_amdgcn_s_setprio(1);
#pragma unroll
      for (int mi = 0; mi < MI; ++mi)
#pragma unroll
        for (int ni = 0; ni < NI; ++ni)
          acc[mi][ni] = __builtin_amdgcn_mfma_f32_16x16x32_bf16(af[mi], bfr[ni],
                                                                acc[mi][ni], 0, 0, 0);
      __builtin_amdgcn_s_setprio(0);
    }
    __builtin_amdgcn_s_barrier();
    SCHEDB();
  }

  // epilogue (ks>=2 partials land in out2: partial2 at +0, partial3 at +outKsStride)
  float* outF = (ks < 2) ? ((float*)out + (size_t)ks * outKsStride)
                         : ((float*)out2 + (size_t)(ks - 2) * outKsStride);
#pragma unroll
  for (int ni = 0; ni < NI; ++ni) {
    const int col = nt * BN + wn + ni * 16 + lr;
    const float bv = bias ? bias[e * biasStride + col] : 0.0f;
#pragma unroll
    for (int mi = 0; mi < MI; ++mi) {
      const int row0 = mrow0 + wrow + mi * 16 + lg * 4;
#pragma unroll
      for (int r = 0; r < 4; ++r) {
        float v = acc[mi][ni][r] + bv;
        if (ACT == 1) v = 0.5f * v * (1.0f + erff(v * 0.70710678118654752f));  // exact GELU
        if (OB16) ((short*)out)[(size_t)(row0 + r) * outLd + col] = f2bf(v);
        else      outF[(size_t)(row0 + r) * outLd + col] = v;
      }
    }
  }
}

// ---------------- fused attention ----------------
__global__ void attn_kernel(const short* __restrict__ QKV, const float* __restrict__ mask,
                            short* __restrict__ ctx) {
  __shared__ __align__(16) short Vt[2][64 * 40];
  __shared__ __align__(16) short Pt[4][2][16 * 40];
  const int bh = blockIdx.x;
  const int b = bh / CNH, h = bh % CNH;
  const int qt = blockIdx.y;
  const int t = threadIdx.x, w = t >> 6, l = t & 63, lr = l & 15, lg = l >> 4;

  const size_t bS = (size_t)b * CS;
  const short* Qh = QKV + bS * C3H + h * CDH;
  const short* Kh = Qh + CH;
  const short* Vh = Qh + 2 * CH;
  const float* mrow = mask + bS;

  const int qrow = qt * 64 + w * 16 + lr;
  bf16x8 qa[2];
  qa[0] = *(const bf16x8*)(Qh + (size_t)qrow * C3H + lg * 8);
  qa[1] = *(const bf16x8*)(Qh + (size_t)qrow * C3H + 32 + lg * 8);

  f32x4 o[4] = {};
  float lp[4] = {0.f, 0.f, 0.f, 0.f};

  const int dh = t & 63, kg = t >> 6;
  {
    short v8[8];
#pragma unroll
    for (int j = 0; j < 8; ++j) v8[j] = Vh[(size_t)(kg * 8 + j) * C3H + dh];
    uint32_t p0 = (uint32_t)(uint16_t)v8[0] | ((uint32_t)(uint16_t)v8[1] << 16);
    uint32_t p1 = (uint32_t)(uint16_t)v8[2] | ((uint32_t)(uint16_t)v8[3] << 16);
    uint32_t p2 = (uint32_t)(uint16_t)v8[4] | ((uint32_t)(uint16_t)v8[5] << 16);
    uint32_t p3 = (uint32_t)(uint16_t)v8[6] | ((uint32_t)(uint16_t)v8[7] << 16);
    uint4 pk = {p0, p1, p2, p3};
    *(uint4*)(&Vt[0][dh * 40 + kg * 8]) = pk;
  }

  for (int tt = 0; tt < CS / 32; ++tt) {
    const int k0 = tt * 32;
    __syncthreads();

    f32x4 sacc[2] = {};
#pragma unroll
    for (int n = 0; n < 2; ++n) {
      bf16x8 kb0 = *(const bf16x8*)(Kh + (size_t)(k0 + n * 16 + lr) * C3H + lg * 8);
      bf16x8 kb1 = *(const bf16x8*)(Kh + (size_t)(k0 + n * 16 + lr) * C3H + 32 + lg * 8);
      sacc[n] = __builtin_amdgcn_mfma_f32_16x16x32_bf16(qa[0], kb0, sacc[n], 0, 0, 0);
      sacc[n] = __builtin_amdgcn_mfma_f32_16x16x32_bf16(qa[1], kb1, sacc[n], 0, 0, 0);
    }

    if (tt + 1 < CS / 32) {
      const int k1 = k0 + 32;
      short v8[8];
#pragma unroll
      for (int j = 0; j < 8; ++j) v8[j] = Vh[(size_t)(k1 + kg * 8 + j) * C3H + dh];
      uint32_t p0 = (uint32_t)(uint16_t)v8[0] | ((uint32_t)(uint16_t)v8[1] << 16);
      uint32_t p1 = (uint32_t)(uint16_t)v8[2] | ((uint32_t)(uint16_t)v8[3] << 16);
      uint32_t p2 = (uint32_t)(uint16_t)v8[4] | ((uint32_t)(uint16_t)v8[5] << 16);
      uint32_t p3 = (uint32_t)(uint16_t)v8[6] | ((uint32_t)(uint16_t)v8[7] << 16);
      uint4 pk = {p0, p1, p2, p3};
      *(uint4*)(&Vt[(tt + 1) & 1][dh * 40 + kg * 8]) = pk;
    }

    const int pb = tt & 1;
#pragma unroll
    for (int n = 0; n < 2; ++n) {
      float mv = mrow[k0 + n * 16 + lr];
#pragma unroll
      for (int r = 0; r < 4; ++r) {
        float s = sacc[n][r] * 0.125f + mv;
        float e = __expf(s);
        lp[r] += e;
        Pt[w][pb][(lg * 4 + r) * 40 + n * 16 + lr] = f2bf(e);
      }
    }

    bf16x8 pa = *(const bf16x8*)(&Pt[w][pb][lr * 40 + lg * 8]);
#pragma unroll
    for (int d = 0; d < 4; ++d) {
      bf16x8 vbf = *(const bf16x8*)(&Vt[tt & 1][(d * 16 + lr) * 40 + lg * 8]);
      o[d] = __builtin_amdgcn_mfma_f32_16x16x32_bf16(pa, vbf, o[d], 0, 0, 0);
    }
  }

#pragma unroll
  for (int r = 0; r < 4; ++r) {
    float s = lp[r];
    s += __shfl_xor(s, 1); s += __shfl_xor(s, 2);
    s += __shfl_xor(s, 4); s += __shfl_xor(s, 8);
    lp[r] = 1.0f / s;
  }
#pragma unroll
  for (int d = 0; d < 4; ++d)
#pragma unroll
    for (int r = 0; r < 4; ++r) {
      int row = qt * 64 + w * 16 + lg * 4 + r;
      ctx[(bS + row) * CH + h * CDH + d * 16 + lr] = f2bf(o[d][r] * lp[r]);
    }
}

// ---------------- unified LN: NP split-K partials + expert bias + residual
// -> LayerNorm -> f32 out (+ optional bf16 out) -------------------
template <int NP>
__global__ void ln12_kernel(const float* __restrict__ p0, const float* __restrict__ p1,
                            const float* __restrict__ p2, const float* __restrict__ p3,
                            const float* __restrict__ res,
                            const float* __restrict__ btab, const int* __restrict__ eidx,
                            const float* __restrict__ g, const float* __restrict__ bta,
                            float* __restrict__ out32, short* __restrict__ out16) {
  const int row = blockIdx.x;
  const int l = threadIdx.x;
  const int e = eidx[row >> 9];
  const float* xr0 = p0 + (size_t)row * CH;
  const float* xr1 = p1 + (size_t)row * CH;
  const float* rr  = res + (size_t)row * CH;
  const float* bo  = btab + (size_t)e * CH;
  float4 v[3];
  float sum = 0.f, ss = 0.f;
#pragma unroll
  for (int j = 0; j < 3; ++j) {
    float4 a = *(const float4*)(xr0 + j * 256 + l * 4);
    float4 c = *(const float4*)(xr1 + j * 256 + l * 4);
    float4 b = *(const float4*)(rr + j * 256 + l * 4);
    float4 bb = *(const float4*)(bo + j * 256 + l * 4);
    a.x += c.x + b.x + bb.x; a.y += c.y + b.y + bb.y;
    a.z += c.z + b.z + bb.z; a.w += c.w + b.w + bb.w;
    if (NP >= 3) {
      float4 d2 = *(const float4*)(p2 + (size_t)row * CH + j * 256 + l * 4);
      a.x += d2.x; a.y += d2.y; a.z += d2.z; a.w += d2.w;
    }
    if (NP == 4) {
      float4 d3 = *(const float4*)(p3 + (size_t)row * CH + j * 256 + l * 4);
      a.x += d3.x; a.y += d3.y; a.z += d3.z; a.w += d3.w;
    }
    v[j] = a;
    sum += a.x + a.y + a.z + a.w;
    ss  += a.x * a.x + a.y * a.y + a.z * a.z + a.w * a.w;
  }
#pragma unroll
  for (int m = 1; m < 64; m <<= 1) { sum += __shfl_xor(sum, m); ss += __shfl_xor(ss, m); }
  const float mean = sum * (1.0f / CH);
  const float var  = ss * (1.0f / CH) - mean * mean;
  const float rstd = rsqrtf(var + 1e-12f);
#pragma unroll
  for (int j = 0; j < 3; ++j) {
    float4 gg = *(const float4*)(g   + j * 256 + l * 4);
    float4 bb = *(const float4*)(bta + j * 256 + l * 4);
    float4 a = v[j], y;
    y.x = (a.x - mean) * rstd * gg.x + bb.x;
    y.y = (a.y - mean) * rstd * gg.y + bb.y;
    y.z = (a.z - mean) * rstd * gg.z + bb.z;
    y.w = (a.w - mean) * rstd * gg.w + bb.w;
    *(float4*)(out32 + (size_t)row * CH + j * 256 + l * 4) = y;
    if (out16) {
      short4 o;
      o.x = f2bf(y.x); o.y = f2bf(y.y); o.z = f2bf(y.z); o.w = f2bf(y.w);
      *(short4*)(out16 + (size_t)row * CH + j * 256 + l * 4) = o;
    }
  }
}

// ---------------- launcher ----------------
extern "C" void kernel_launch(void* const* d_in, const int* in_sizes, int n_in,
                              void* d_out, int out_size, void* d_ws, size_t ws_size,
                              hipStream_t stream) {
  (void)in_sizes; (void)n_in; (void)out_size; (void)ws_size;
  const float* hidden = (const float*)d_in[0];
  const int*   eidx   = (const int*)d_in[1];
  const float* mask   = (const float*)d_in[2];
  const float* Wq   = (const float*)d_in[3];
  const float* bq   = (const float*)d_in[4];
  const float* Wk   = (const float*)d_in[5];
  const float* bk   = (const float*)d_in[6];
  const float* Wv   = (const float*)d_in[7];
  const float* bv   = (const float*)d_in[8];
  const float* Wo   = (const float*)d_in[9];
  const float* bo   = (const float*)d_in[10];
  const float* ln1g = (const float*)d_in[11];
  const float* ln1b = (const float*)d_in[12];
  const float* Wi   = (const float*)d_in[13];
  const float* bi   = (const float*)d_in[14];
  const float* Wout = (const float*)d_in[15];
  const float* bout = (const float*)d_in[16];
  const float* ln2g = (const float*)d_in[17];
  const float* ln2b = (const float*)d_in[18];

  char* ws = (char*)d_ws;
  size_t off = 0;
  auto alloc = [&](size_t bytes) {
    void* p = ws + off;
    off += (bytes + 255) & ~(size_t)255;
    return p;
  };
  const size_t M = (size_t)CB * CS;                    // 4096 rows
  short* Xb    = (short*)alloc(M * CH * 2);            // later reused as x1b
  char*  Rbig  = (char*)alloc(M * CFF * 2);            // QKVb then hmid
  char*  Rcx   = (char*)alloc(M * CH * 4);             // ctxb then x1
  float* parts = (float*)alloc(2 * M * CH * 4);        // split-K partials 0,1
  float* qkvbias = (float*)alloc(CE * C3H * 4);
  short* Wqkvt = (short*)alloc((size_t)CE * C3H * CH * 2);  // 14.2 MB
  short* Wot   = (short*)alloc((size_t)CE * CH * CH * 2);   // 4.7 MB
  short* Wit   = (short*)alloc((size_t)CE * CH * CFF * 2);  // 18.9 MB
  short* Wo2t  = (short*)alloc((size_t)CE * CFF * CH * 2);
  short* QKVb = (short*)Rbig;
  short* hmid = (short*)Rbig;
  short* ctxb = (short*)Rcx;
  float* x1   = (float*)Rcx;
  short* x1b  = Xb;
  // FFN2 partials 2,3 overlay dead weight regions: partial2 at Wqkvt base,
  // partial3 at Wqkvt + M*CH floats -> spans Wqkvt tail + Wot + Wit head,
  // all dead after step 6.  LN2 reads the SAME addresses.
  float* pp2  = (float*)Wqkvt;
  float* pp3  = pp2 + M * CH;

  // 1. prep
  const int n4 = (int)(M * CH / 4);
  cvt_bf16_kernel<<<(n4 + 255) / 256, 256, 0, stream>>>(hidden, Xb, n4);
  tpose4_kernel<<<dim3(CH / 64, CH / 64, 4 * CE), 256, 0, stream>>>(Wq, Wk, Wv, Wo, eidx, Wqkvt, Wot);
  tpose_cvt_kernel<<<dim3(CFF / 64, CH / 64, CE), 256, 0, stream>>>(Wi, Wit, eidx, CH, CFF);
  tpose_cvt_kernel<<<dim3(CH / 64, CFF / 64, CE), 256, 0, stream>>>(Wout, Wo2t, eidx, CFF, CH);
  qkv_bias_kernel<<<(CE * C3H + 255) / 256, 256, 0, stream>>>(bq, bk, bv, qkvbias);

  // 2. QKV fused GEMM: grid 384, NT=6
  gemm8_kernel<CH, 12, 1, 4, 2, 0, true><<<384, 256, 0, stream>>>(
      Xb, Wqkvt, qkvbias, eidx, (char*)QKVb, nullptr, (size_t)C3H * CH, C3H, C3H, 0);
  // 3. attention
  attn_kernel<<<dim3(CB * CNH, CS / 64), 256, 0, stream>>>(QKVb, mask, ctxb);
  // 4. O projection: splitK2, grid 256, NT=3 (bias folded into LN1)
  gemm8_kernel<CH, 4, 2, 4, 1, 0, false><<<256, 256, 0, stream>>>(
      ctxb, Wot, nullptr, eidx, (char*)parts, nullptr, (size_t)CH * CH, CH, CH, M * CH);
  // 5. LN1 (2 partials + bo + residual hidden) -> x1 f32 + x1b bf16
  ln12_kernel<2><<<(int)M, 64, 0, stream>>>(parts, parts + M * CH, nullptr, nullptr,
                                            hidden, bo, eidx, ln1g, ln1b, x1, x1b);
  // 6. FFN intermediate + GELU: grid 512 (exact 2/CU), NT=6
  gemm8_kernel<CH, 16, 1, 4, 2, 1, true><<<512, 256, 0, stream>>>(
      x1b, Wit, bi, eidx, (char*)hmid, nullptr, (size_t)CH * CFF, CFF, CFF, 0);
  // 7. FFN output: splitK4 (K/4=384 = 3 K-tiles), grid 512 (exact 2/CU)
  gemm8_kernel<CFF, 4, 4, 2, 1, 0, false><<<512, 256, 0, stream>>>(
      hmid, Wo2t, nullptr, eidx, (char*)parts, (char*)pp2, (size_t)CFF * CH, CH, CH, M * CH);
  // 8. LN2 (4 partials + bout + residual x1) -> d_out
  ln12_kernel<4><<<(int)M, 64, 0, stream>>>(parts, parts + M * CH, pp2, pp3,
                                            x1, bout, eidx, ln2g, ln2b, (float*)d_out, nullptr);
}